// Round 10
// baseline (204.524 us; speedup 1.0000x reference)
//
#include <hip/hip_runtime.h>
#include <hip/hip_bf16.h>

#define N 8192
#define D 1024
#define MARGIN 1.0f
#define EPS 1e-6f

typedef __attribute__((ext_vector_type(8))) short bf16x8;
typedef __attribute__((ext_vector_type(4))) float f32x4;
typedef __attribute__((ext_vector_type(8))) _Float16 f16x8;
typedef __attribute__((ext_vector_type(4))) _Float16 f16x4;
typedef __attribute__((ext_vector_type(8))) unsigned short u16x8;

__device__ inline unsigned short f2bf(float x) {
    unsigned u = __float_as_uint(x);
    unsigned r = (u + 0x7FFFu + ((u >> 16) & 1u)) >> 16;  // RNE
    return (unsigned short)r;
}

__device__ inline float h2f(unsigned hb) {
    return (float)__builtin_bit_cast(_Float16, (unsigned short)hb);
}

__device__ inline unsigned h2u(float d2) {
    return (unsigned)__builtin_bit_cast(unsigned short, (_Float16)d2);
}

// Kernel 0: fp32 -> bf16 copy + per-row sum of squares + cls + reduction-array
// init. One row per WAVE (4 rows/block, no LDS/barriers).
__global__ __launch_bounds__(256) void prep_kernel(const float* __restrict__ E,
                                                   const int* __restrict__ target,
                                                   unsigned short* __restrict__ Ebf,
                                                   float* __restrict__ sq,
                                                   unsigned char* __restrict__ cls,
                                                   unsigned* __restrict__ pmG,
                                                   unsigned* __restrict__ nmG,
                                                   unsigned* __restrict__ smG) {
    const int tid = threadIdx.x;
    const int lane = tid & 63, wave = tid >> 6;
    const int r = blockIdx.x * 4 + wave;
    const float4 v = ((const float4*)(E + (size_t)r * D))[lane];
    ushort4 o;
    o.x = f2bf(v.x); o.y = f2bf(v.y); o.z = f2bf(v.z); o.w = f2bf(v.w);
    ((ushort4*)(Ebf + (size_t)r * D))[lane] = o;
    float s = v.x * v.x + v.y * v.y + v.z * v.z + v.w * v.w;
    for (int off = 32; off > 0; off >>= 1) s += __shfl_down(s, off);
    if (lane == 0) {
        sq[r] = s;
        cls[r] = (unsigned char)target[r];
        pmG[r] = 0u;
        nmG[r] = 0xFFFFFFFFu;
        smG[r] = 0xFFFFFFFFu;
    }
}

// ---------------------------------------------------------------------------
// Kernel 1: ids 0..495 strict-lower 256^2 tiles (R8 row-major decode -- the
// fastest measured config; R9's band order cut FETCH 40MB but SLOWED the loop,
// falsifying fetch-boundedness). ids 496..591 = diag 128^2 lights.
// R10: mirror tile ELIMINATED. Epilogue writes only the direct (lower) tile
// and folds pm (max same-class) / nm (min diff-class) reductions for BOTH the
// row-side and column-side into LDS+global atomics. Semi-hard sm moves to
// mine2 (needs global pm first).
// ---------------------------------------------------------------------------

#define SLOT_0A0 0
#define SLOT_0A1 16384
#define SLOT_0B0 32768
#define SLOT_0B1 49152
#define SLOT_1A0 65536
#define SLOT_1A1 81920
#define SLOT_1B0 98304
#define SLOT_1B1 114688

#define VMW(n) __asm__ __volatile__("s_waitcnt vmcnt(" #n ")" ::: "memory")
#define NOSTAGE ((void)0)
#define NOWAIT ((void)0)

#define STAGE(slotOff, baseRow, kcol) do {                                              \
    const unsigned short* _s0 = E + (size_t)((baseRow) + (tid >> 2)) * D + (kcol) + stc * 8; \
    __builtin_amdgcn_global_load_lds(                                                    \
        (const __attribute__((address_space(1))) unsigned int*)_s0,                      \
        (__attribute__((address_space(3))) unsigned int*)(smem + (slotOff) + wave * 1024), 16, 0, 0); \
    const unsigned short* _s1 = _s0 + (size_t)128 * D;                                   \
    __builtin_amdgcn_global_load_lds(                                                    \
        (const __attribute__((address_space(1))) unsigned int*)_s1,                      \
        (__attribute__((address_space(3))) unsigned int*)(smem + (slotOff) + 8192 + wave * 1024), 16, 0, 0); \
} while (0)

#define PHASE(b, ks, mq, LOADB, STG, WAIT) do {                                          \
    const char* _As = smem + (b) * 65536 + (ks) * 16384;                                 \
    const char* _Bs = smem + (b) * 65536 + 32768 + (ks) * 16384;                         \
    if (LOADB) {                                                                         \
        _Pragma("unroll") for (int nj = 0; nj < 4; ++nj)                                 \
            bfr[nj] = *(const bf16x8*)(_Bs + (wn * 64 + nj * 16 + mr) * 64 + swz);       \
    }                                                                                    \
    bf16x8 af[4];                                                                        \
    _Pragma("unroll") for (int mi = 0; mi < 4; ++mi)                                     \
        af[mi] = *(const bf16x8*)(_As + (wm * 128 + (mq) * 64 + mi * 16 + mr) * 64 + swz); \
    STG;                                                                                 \
    __builtin_amdgcn_s_setprio(1);                                                       \
    _Pragma("unroll") for (int mi = 0; mi < 4; ++mi)                                     \
        _Pragma("unroll") for (int nj = 0; nj < 4; ++nj)                                 \
            acc[(mq) * 4 + mi][nj] = __builtin_amdgcn_mfma_f32_16x16x32_bf16(            \
                af[mi], bfr[nj], acc[(mq) * 4 + mi][nj], 0, 0, 0);                       \
    __builtin_amdgcn_s_setprio(0);                                                       \
    WAIT;                                                                                \
    __asm__ __volatile__("s_barrier" ::: "memory");                                      \
} while (0)

// Light path: one 128^2 diagonal sub-tile, 512 threads / 8 waves (each 64x32),
// 4-slot LDS ring, counted vmcnt(4), last 2 iterations peeled. Writes the
// direct tile + pm/nm row/col reductions (no mirror).
__device__ __forceinline__ void diag_path(char* smem,
                                          const unsigned short* __restrict__ E,
                                          const float* __restrict__ sq,
                                          const unsigned char* __restrict__ cls,
                                          _Float16* __restrict__ D2h,
                                          unsigned* __restrict__ pmG,
                                          unsigned* __restrict__ nmG,
                                          const int c, const int tid) {
    const int lane = tid & 63;
    const int wave = tid >> 6;           // 0..7
    const int wmL = wave >> 2;           // 0..1 : 64-row half
    const int wnL = wave & 3;            // 0..3 : 32-col quarter
    const int mr = lane & 15;
    const int q = lane >> 4;
    const int kq = q * 8;

    const int t = c / 3, s = c - 3 * t;
    const int smi = (s + 1) >> 1;        // 0,1,1
    const int sni = s >> 1;              // 0,0,1
    const int rm = t * 256 + smi * 128;
    const int cn = t * 256 + sni * 128;

    f32x4 acc[4][2] = {};

#define DSTAGE(sl, kk) do {                                                              \
    __builtin_amdgcn_global_load_lds(                                                    \
        (const __attribute__((address_space(1))) unsigned int*)(E + (size_t)(rm + (tid >> 2)) * D + (kk) * 32 + (tid & 3) * 8), \
        (__attribute__((address_space(3))) unsigned int*)(smem + (sl) * 32768 + wave * 1024), 16, 0, 0); \
    __builtin_amdgcn_global_load_lds(                                                    \
        (const __attribute__((address_space(1))) unsigned int*)(E + (size_t)(cn + (tid >> 2)) * D + (kk) * 32 + (tid & 3) * 8), \
        (__attribute__((address_space(3))) unsigned int*)(smem + (sl) * 32768 + 16384 + wave * 1024), 16, 0, 0); \
} while (0)

#define DCOMPUTE(k) do {                                                                 \
    const unsigned short* As = (const unsigned short*)(smem + (size_t)((k) & 3) * 32768);\
    const unsigned short* Bs = As + 8192;                                                \
    bf16x8 af[4], bfv[2];                                                                \
    _Pragma("unroll") for (int mi = 0; mi < 4; ++mi)                                     \
        af[mi] = *(const bf16x8*)(As + (wmL * 64 + mi * 16 + mr) * 32 + kq);             \
    _Pragma("unroll") for (int ni = 0; ni < 2; ++ni)                                     \
        bfv[ni] = *(const bf16x8*)(Bs + (wnL * 32 + ni * 16 + mr) * 32 + kq);            \
    _Pragma("unroll") for (int mi = 0; mi < 4; ++mi)                                     \
        _Pragma("unroll") for (int ni = 0; ni < 2; ++ni)                                 \
            acc[mi][ni] = __builtin_amdgcn_mfma_f32_16x16x32_bf16(af[mi], bfv[ni], acc[mi][ni], 0, 0, 0); \
} while (0)

    DSTAGE(0, 0);
    DSTAGE(1, 1);
    for (int k = 0; k < 30; ++k) {
        DSTAGE((k + 2) & 3, k + 2);
        __asm__ __volatile__("s_waitcnt vmcnt(4)" ::: "memory");
        __asm__ __volatile__("s_barrier" ::: "memory");
        DCOMPUTE(k);
    }
    __asm__ __volatile__("s_waitcnt vmcnt(2)" ::: "memory");
    __asm__ __volatile__("s_barrier" ::: "memory");
    DCOMPUTE(30);
    __asm__ __volatile__("s_waitcnt vmcnt(0)" ::: "memory");
    __asm__ __volatile__("s_barrier" ::: "memory");
    DCOMPUTE(31);
#undef DSTAGE
#undef DCOMPUTE
    __syncthreads();

    // cls for this lane's columns (2) and sq values
    unsigned ccbL[2];
    float sqjL[2];
#pragma unroll
    for (int ni = 0; ni < 2; ++ni) {
        const int col = cn + wnL * 32 + ni * 16 + mr;
        sqjL[ni] = sq[col];
        ccbL[ni] = cls[col];
    }

    // direct-tile store (scalar; 32 KB/tile, negligible traffic)
#pragma unroll
    for (int mi = 0; mi < 4; ++mi) {
        const int i0 = rm + wmL * 64 + mi * 16 + q * 4;
        const f32x4 sqi = *(const f32x4*)(sq + i0);
#pragma unroll
        for (int ni = 0; ni < 2; ++ni) {
            const int j = cn + wnL * 32 + ni * 16 + mr;
#pragma unroll
            for (int r = 0; r < 4; ++r) {
                const float d2 = fmaxf(sqi[r] + sqjL[ni] - 2.0f * acc[mi][ni][r], 0.0f);
                D2h[(size_t)(i0 + r) * N + j] = (_Float16)d2;
            }
        }
    }

    // pm/nm reductions (smem reused: 4 arrays of 128 u32 = 2 KB)
    unsigned* pmRowL = (unsigned*)smem;
    unsigned* nmRowL = pmRowL + 128;
    unsigned* pmColL = pmRowL + 256;
    unsigned* nmColL = pmRowL + 384;
    if (tid < 128)       pmRowL[tid] = 0u;
    else if (tid < 256)  nmRowL[tid - 128] = 0xFFFFFFFFu;
    else if (tid < 384)  pmColL[tid - 256] = 0u;
    else                 nmColL[tid - 384] = 0xFFFFFFFFu;
    __syncthreads();

    unsigned cpm[2] = {0u, 0u}, cnm[2] = {0xFFFFu, 0xFFFFu};
#pragma unroll
    for (int mi = 0; mi < 4; ++mi) {
        const int i0 = rm + wmL * 64 + mi * 16 + q * 4;
        const unsigned clsR = *(const unsigned*)(cls + i0);
        const f32x4 sqi = *(const f32x4*)(sq + i0);
        unsigned rpm[4] = {0u, 0u, 0u, 0u};
        unsigned rnm[4] = {0xFFFFu, 0xFFFFu, 0xFFFFu, 0xFFFFu};
#pragma unroll
        for (int ni = 0; ni < 2; ++ni) {
#pragma unroll
            for (int r = 0; r < 4; ++r) {
                const unsigned v = h2u(fmaxf(sqi[r] + sqjL[ni] - 2.0f * acc[mi][ni][r], 0.0f));
                const bool same = ((clsR >> (8 * r)) & 0xFFu) == ccbL[ni];
                rpm[r] = max(rpm[r], same ? v : 0u);
                rnm[r] = min(rnm[r], same ? 0xFFFFu : v);
                cpm[ni] = max(cpm[ni], same ? v : 0u);
                cnm[ni] = min(cnm[ni], same ? 0xFFFFu : v);
            }
        }
#pragma unroll
        for (int r = 0; r < 4; ++r) {
            for (int off = 1; off < 16; off <<= 1) {
                rpm[r] = max(rpm[r], (unsigned)__shfl_xor((int)rpm[r], off));
                rnm[r] = min(rnm[r], (unsigned)__shfl_xor((int)rnm[r], off));
            }
            if (mr == 0) {
                const int li = wmL * 64 + mi * 16 + q * 4 + r;
                atomicMax(&pmRowL[li], rpm[r]);
                atomicMin(&nmRowL[li], rnm[r]);
            }
        }
    }
#pragma unroll
    for (int ni = 0; ni < 2; ++ni) {
        cpm[ni] = max(cpm[ni], (unsigned)__shfl_xor((int)cpm[ni], 16));
        cpm[ni] = max(cpm[ni], (unsigned)__shfl_xor((int)cpm[ni], 32));
        cnm[ni] = min(cnm[ni], (unsigned)__shfl_xor((int)cnm[ni], 16));
        cnm[ni] = min(cnm[ni], (unsigned)__shfl_xor((int)cnm[ni], 32));
        if (q == 0) {
            const int lj = wnL * 32 + ni * 16 + mr;
            atomicMax(&pmColL[lj], cpm[ni]);
            atomicMin(&nmColL[lj], cnm[ni]);
        }
    }
    __syncthreads();
    if (tid < 128) {
        atomicMax(&pmG[rm + tid], pmRowL[tid]);
        atomicMin(&nmG[rm + tid], nmRowL[tid]);
    } else if (tid < 256) {
        const int c2 = tid - 128;
        atomicMax(&pmG[cn + c2], pmColL[c2]);
        atomicMin(&nmG[cn + c2], nmColL[c2]);
    }
}

__global__ __launch_bounds__(512, 2) void gemm_kernel(const unsigned short* __restrict__ E,
                                                      const float* __restrict__ sq,
                                                      const unsigned char* __restrict__ cls,
                                                      _Float16* __restrict__ D2h,
                                                      unsigned* __restrict__ pmG,
                                                      unsigned* __restrict__ nmG) {
    extern __shared__ char smem[];

    const int tid = threadIdx.x;            // 0..511

    if (blockIdx.x >= 496) {
        diag_path(smem, E, sq, cls, D2h, pmG, nmG, blockIdx.x - 496, tid);
        return;
    }

    const int lane = tid & 63;
    const int wave = tid >> 6;              // 0..7
    const int wm = wave >> 2;               // M-half (128 rows)
    const int wn = wave & 3;                // N-quarter (64 cols)
    const int mr = lane & 15;
    const int q = lane >> 4;
    const int swz = ((q ^ ((mr >> 1) & 3)) << 4);   // ds_read chunk swizzle
    const int stc = (tid & 3) ^ ((tid >> 3) & 3);   // stage source chunk (inverse swz)

    // R8 row-major decode + XCD swizzle (fastest measured config)
    const int h = blockIdx.x;
    const int l = (h & 7) * 62 + (h >> 3);
    int by = (int)((1.0f + sqrtf(8.0f * (float)l + 1.0f)) * 0.5f);
    while (by * (by - 1) / 2 > l) --by;
    while ((by + 1) * by / 2 <= l) ++by;
    const int bx = l - by * (by - 1) / 2;
    const int rm = by * 256;
    const int cn = bx * 256;

    f32x4 acc[8][4] = {};
    bf16x8 bfr[4];

    STAGE(SLOT_0A0, rm, 0);
    STAGE(SLOT_0B0, cn, 0);
    STAGE(SLOT_0A1, rm, 32);
    STAGE(SLOT_0B1, cn, 32);
    STAGE(SLOT_1A0, rm, 64);
    VMW(6);
    __asm__ __volatile__("s_barrier" ::: "memory");

    for (int i = 0; i < 7; ++i) {
        const int kt = 2 * i;
        PHASE(0, 0, 0, 1, STAGE(SLOT_1B0, cn, (kt + 1) * 64 + 0),  NOWAIT);
        PHASE(0, 0, 1, 0, STAGE(SLOT_1A1, rm, (kt + 1) * 64 + 32), VMW(6));
        PHASE(0, 1, 0, 1, STAGE(SLOT_1B1, cn, (kt + 1) * 64 + 32), NOWAIT);
        PHASE(0, 1, 1, 0, STAGE(SLOT_0A0, rm, (kt + 2) * 64 + 0),  VMW(6));
        PHASE(1, 0, 0, 1, STAGE(SLOT_0B0, cn, (kt + 2) * 64 + 0),  NOWAIT);
        PHASE(1, 0, 1, 0, STAGE(SLOT_0A1, rm, (kt + 2) * 64 + 32), VMW(6));
        PHASE(1, 1, 0, 1, STAGE(SLOT_0B1, cn, (kt + 2) * 64 + 32), NOWAIT);
        PHASE(1, 1, 1, 0, STAGE(SLOT_1A0, rm, (kt + 3) * 64 + 0),  VMW(6));
    }
    PHASE(0, 0, 0, 1, STAGE(SLOT_1B0, cn, 15 * 64 + 0),  NOWAIT);
    PHASE(0, 0, 1, 0, STAGE(SLOT_1A1, rm, 15 * 64 + 32), VMW(6));
    PHASE(0, 1, 0, 1, STAGE(SLOT_1B1, cn, 15 * 64 + 32), NOWAIT);
    PHASE(0, 1, 1, 0, NOSTAGE, VMW(4));
    PHASE(1, 0, 0, 1, NOSTAGE, NOWAIT);
    PHASE(1, 0, 1, 0, NOSTAGE, VMW(0));
    PHASE(1, 1, 0, 1, NOSTAGE, NOWAIT);
    PHASE(1, 1, 1, 0, NOSTAGE, NOWAIT);

    __asm__ __volatile__("s_waitcnt lgkmcnt(0)" ::: "memory");
    __asm__ __volatile__("s_barrier" ::: "memory");

    const int crow = q * 4;
    float sqj[4];
    unsigned ccb[4];
#pragma unroll
    for (int nj = 0; nj < 4; ++nj) {
        const int col = cn + wn * 64 + nj * 16 + mr;
        sqj[nj] = sq[col];
        ccb[nj] = cls[col];
    }
    float sqiv[8][4];
#pragma unroll
    for (int mg = 0; mg < 8; ++mg) {
        const f32x4 s4 = *(const f32x4*)(sq + rm + wm * 128 + mg * 16 + crow);
#pragma unroll
        for (int r = 0; r < 4; ++r) sqiv[mg][r] = s4[r];
    }

    // ---- pass 1: direct tile -> LDS (swizzled) -> streamed 512B rows ----
#pragma unroll
    for (int mg = 0; mg < 8; ++mg) {
        const int ilocb = wm * 128 + mg * 16 + crow;
#pragma unroll
        for (int nj = 0; nj < 4; ++nj) {
            const int jloc = wn * 64 + nj * 16 + mr;
            const unsigned jc = (unsigned)jloc >> 3;
            const unsigned jo = ((unsigned)jloc & 7) << 1;
#pragma unroll
            for (int r = 0; r < 4; ++r) {
                const float d2 = fmaxf(sqiv[mg][r] + sqj[nj] - 2.0f * acc[mg][nj][r], 0.0f);
                const int row = ilocb + r;
                *(_Float16*)(smem + (size_t)row * 512 + ((jc ^ (row & 31)) << 4) + jo) = (_Float16)d2;
            }
        }
    }
    __asm__ __volatile__("s_waitcnt lgkmcnt(0)" ::: "memory");
    __asm__ __volatile__("s_barrier" ::: "memory");
    {
        const int seg = tid & 31;
#pragma unroll
        for (int it = 0; it < 16; ++it) {
            const int rt = it * 16 + (tid >> 5);
            f16x8 v = *(const f16x8*)(smem + (size_t)rt * 512 + (((unsigned)seg ^ (rt & 31)) << 4));
            *(f16x8*)(D2h + (size_t)(rm + rt) * N + cn + seg * 8) = v;
        }
    }
    __asm__ __volatile__("s_waitcnt lgkmcnt(0)" ::: "memory");
    __asm__ __volatile__("s_barrier" ::: "memory");

    // ---- pass 2: pm/nm reductions (smem reused: 4 arrays of 256 u32) ----
    unsigned* pmRow = (unsigned*)smem;
    unsigned* nmRow = pmRow + 256;
    unsigned* pmCol = pmRow + 512;
    unsigned* nmCol = pmRow + 768;
    if (tid < 256) { pmRow[tid] = 0u; nmRow[tid] = 0xFFFFFFFFu; }
    else           { pmCol[tid - 256] = 0u; nmCol[tid - 256] = 0xFFFFFFFFu; }
    __syncthreads();

    unsigned cpm[4] = {0u, 0u, 0u, 0u};
    unsigned cnm[4] = {0xFFFFu, 0xFFFFu, 0xFFFFu, 0xFFFFu};
#pragma unroll
    for (int mg = 0; mg < 8; ++mg) {
        const unsigned clsR = *(const unsigned*)(cls + rm + wm * 128 + mg * 16 + crow);
        unsigned rpm[4] = {0u, 0u, 0u, 0u};
        unsigned rnm[4] = {0xFFFFu, 0xFFFFu, 0xFFFFu, 0xFFFFu};
#pragma unroll
        for (int nj = 0; nj < 4; ++nj) {
#pragma unroll
            for (int r = 0; r < 4; ++r) {
                const unsigned v = h2u(fmaxf(sqiv[mg][r] + sqj[nj] - 2.0f * acc[mg][nj][r], 0.0f));
                const bool same = ((clsR >> (8 * r)) & 0xFFu) == ccb[nj];
                rpm[r] = max(rpm[r], same ? v : 0u);
                rnm[r] = min(rnm[r], same ? 0xFFFFu : v);
                cpm[nj] = max(cpm[nj], same ? v : 0u);
                cnm[nj] = min(cnm[nj], same ? 0xFFFFu : v);
            }
        }
#pragma unroll
        for (int r = 0; r < 4; ++r) {
            for (int off = 1; off < 16; off <<= 1) {
                rpm[r] = max(rpm[r], (unsigned)__shfl_xor((int)rpm[r], off));
                rnm[r] = min(rnm[r], (unsigned)__shfl_xor((int)rnm[r], off));
            }
            if (mr == 0) {
                const int li = wm * 128 + mg * 16 + crow + r;
                atomicMax(&pmRow[li], rpm[r]);
                atomicMin(&nmRow[li], rnm[r]);
            }
        }
    }
#pragma unroll
    for (int nj = 0; nj < 4; ++nj) {
        cpm[nj] = max(cpm[nj], (unsigned)__shfl_xor((int)cpm[nj], 16));
        cpm[nj] = max(cpm[nj], (unsigned)__shfl_xor((int)cpm[nj], 32));
        cnm[nj] = min(cnm[nj], (unsigned)__shfl_xor((int)cnm[nj], 16));
        cnm[nj] = min(cnm[nj], (unsigned)__shfl_xor((int)cnm[nj], 32));
        if (q == 0) {
            const int lj = wn * 64 + nj * 16 + mr;
            atomicMax(&pmCol[lj], cpm[nj]);
            atomicMin(&nmCol[lj], cnm[nj]);
        }
    }
    __syncthreads();
    if (tid < 256) {
        atomicMax(&pmG[rm + tid], pmRow[tid]);
        atomicMin(&nmG[rm + tid], nmRow[tid]);
    } else {
        const int c2 = tid - 256;
        atomicMax(&pmG[cn + c2], pmCol[c2]);
        atomicMin(&nmG[cn + c2], nmCol[c2]);
    }
}

// ---------------------------------------------------------------------------
// Kernel 2 (mine2): semi-hard pass. Re-reads the lower-triangle tiles (L3-
// resident) once; per element v: row-side candidate if v > pm[row], col-side
// candidate if v > pm[col] (strict > auto-excludes positives & self).
// atomicMin into smG. Same 592-block tile enumeration as gemm.
// ---------------------------------------------------------------------------
__global__ __launch_bounds__(512) void mine2_kernel(const _Float16* __restrict__ D2h,
                                                    const unsigned* __restrict__ pmG,
                                                    unsigned* __restrict__ smG) {
    __shared__ unsigned colMin[256];
    const int tid = threadIdx.x;
    const int lane = tid & 63;

    if (blockIdx.x < 496) {
        const int l = blockIdx.x;
        int by = (int)((1.0f + sqrtf(8.0f * (float)l + 1.0f)) * 0.5f);
        while (by * (by - 1) / 2 > l) --by;
        while ((by + 1) * by / 2 <= l) ++by;
        const int bx = l - by * (by - 1) / 2;
        const int rm = by * 256;
        const int cn = bx * 256;

        const int tr = tid >> 4;           // 0..31
        const int tc = tid & 15;           // 16-col strip
        unsigned pmc[16], cmin[16];
#pragma unroll
        for (int k = 0; k < 16; ++k) { pmc[k] = pmG[cn + tc * 16 + k]; cmin[k] = 0xFFFFu; }
#pragma unroll
        for (int ri = 0; ri < 8; ++ri) {
            const int r = tr + 32 * ri;
            const unsigned short* rp = (const unsigned short*)(D2h + (size_t)(rm + r) * N + cn + tc * 16);
            const u16x8 a = *(const u16x8*)rp;
            const u16x8 b = *(const u16x8*)(rp + 8);
            const unsigned pmr = pmG[rm + r];
            unsigned rmin = 0xFFFFu;
#pragma unroll
            for (int k = 0; k < 8; ++k) {
                const unsigned v = a[k];
                rmin = min(rmin, v > pmr ? v : 0xFFFFu);
                cmin[k] = min(cmin[k], v > pmc[k] ? v : 0xFFFFu);
                const unsigned w = b[k];
                rmin = min(rmin, w > pmr ? w : 0xFFFFu);
                cmin[k + 8] = min(cmin[k + 8], w > pmc[k + 8] ? w : 0xFFFFu);
            }
            for (int off = 1; off < 16; off <<= 1)
                rmin = min(rmin, (unsigned)__shfl_xor((int)rmin, off));
            if (tc == 0) atomicMin(&smG[rm + r], rmin);
        }
#pragma unroll
        for (int k = 0; k < 16; ++k) {
            cmin[k] = min(cmin[k], (unsigned)__shfl_xor((int)cmin[k], 16));
            cmin[k] = min(cmin[k], (unsigned)__shfl_xor((int)cmin[k], 32));
        }
        if (tid < 256) colMin[tid] = 0xFFFFu;
        __syncthreads();
        if (lane < 16) {
#pragma unroll
            for (int k = 0; k < 16; ++k) atomicMin(&colMin[tc * 16 + k], cmin[k]);
        }
        __syncthreads();
        if (tid < 256) atomicMin(&smG[cn + tid], colMin[tid]);
    } else {
        const int c = blockIdx.x - 496;
        const int t = c / 3, s = c - 3 * t;
        const int rm = t * 256 + (((s + 1) >> 1) << 7);
        const int cn = t * 256 + ((s >> 1) << 7);

        const int tr = tid >> 3;           // 0..63
        const int tc = tid & 7;            // 16-col strip (8 strips x 16 = 128)
        unsigned pmc[16], cmin[16];
#pragma unroll
        for (int k = 0; k < 16; ++k) { pmc[k] = pmG[cn + tc * 16 + k]; cmin[k] = 0xFFFFu; }
#pragma unroll
        for (int ri = 0; ri < 2; ++ri) {
            const int r = tr + 64 * ri;
            const unsigned short* rp = (const unsigned short*)(D2h + (size_t)(rm + r) * N + cn + tc * 16);
            const u16x8 a = *(const u16x8*)rp;
            const u16x8 b = *(const u16x8*)(rp + 8);
            const unsigned pmr = pmG[rm + r];
            unsigned rmin = 0xFFFFu;
#pragma unroll
            for (int k = 0; k < 8; ++k) {
                const unsigned v = a[k];
                rmin = min(rmin, v > pmr ? v : 0xFFFFu);
                cmin[k] = min(cmin[k], v > pmc[k] ? v : 0xFFFFu);
                const unsigned w = b[k];
                rmin = min(rmin, w > pmr ? w : 0xFFFFu);
                cmin[k + 8] = min(cmin[k + 8], w > pmc[k + 8] ? w : 0xFFFFu);
            }
            for (int off = 1; off < 8; off <<= 1)
                rmin = min(rmin, (unsigned)__shfl_xor((int)rmin, off));
            if (tc == 0) atomicMin(&smG[rm + r], rmin);
        }
#pragma unroll
        for (int k = 0; k < 16; ++k) {
            cmin[k] = min(cmin[k], (unsigned)__shfl_xor((int)cmin[k], 8));
            cmin[k] = min(cmin[k], (unsigned)__shfl_xor((int)cmin[k], 16));
            cmin[k] = min(cmin[k], (unsigned)__shfl_xor((int)cmin[k], 32));
        }
        if (tid < 128) colMin[tid] = 0xFFFFu;
        __syncthreads();
        if (lane < 8) {
#pragma unroll
            for (int k = 0; k < 16; ++k) atomicMin(&colMin[tc * 16 + k], cmin[k]);
        }
        __syncthreads();
        if (tid < 128) atomicMin(&smG[cn + tid], colMin[tid]);
    }
}

// Kernel 3: per-row loss from pm/sm/nm.
__global__ __launch_bounds__(256) void finalize_kernel(const unsigned* __restrict__ pmG,
                                                       const unsigned* __restrict__ nmG,
                                                       const unsigned* __restrict__ smG,
                                                       float* __restrict__ loss_arr) {
    const int i = blockIdx.x * 256 + threadIdx.x;
    const float lo = h2f(pmG[i] & 0xFFFFu);
    const float dp = sqrtf(lo);
    const float hw = dp + MARGIN;
    const float hi = hw * hw;
    const float smv = h2f(smG[i] & 0xFFFFu);         // 0xFFFF -> NaN -> fallback
    const float dn2 = (smv < hi) ? smv : h2f(nmG[i] & 0xFFFFu);
    loss_arr[i] = fmaxf(dp - sqrtf(dn2) + MARGIN, 0.0f);
}

// Kernel 4: mean over 8192 per-anchor losses.
__global__ __launch_bounds__(256) void reduce_kernel(const float* __restrict__ loss_arr,
                                                     float* __restrict__ out) {
    const int tid = threadIdx.x;
    float s = 0.0f;
    for (int k = tid; k < N; k += 256) s += loss_arr[k];
    for (int off = 32; off > 0; off >>= 1) s += __shfl_down(s, off);
    __shared__ float red[4];
    const int lane = tid & 63, wave = tid >> 6;
    if (lane == 0) red[wave] = s;
    __syncthreads();
    if (tid == 0) out[0] = (red[0] + red[1] + red[2] + red[3]) * (1.0f / N);
}

extern "C" void kernel_launch(void* const* d_in, const int* in_sizes, int n_in,
                              void* d_out, int out_size, void* d_ws, size_t ws_size,
                              hipStream_t stream) {
    const float* E = (const float*)d_in[0];
    const int* target = (const int*)d_in[1];
    float* out = (float*)d_out;
    char* ws = (char*)d_ws;

    // Workspace layout (~144.2 MB):
    unsigned short* Ebf = (unsigned short*)ws;                            // 16 MB
    float* sq        = (float*)(ws + (size_t)16777216);                   // 32 KB
    float* loss_arr  = (float*)(ws + (size_t)16809984);                   // 32 KB
    unsigned char* cls = (unsigned char*)(ws + (size_t)16842752);         // 8 KB (padded 32 KB)
    _Float16* D2h    = (_Float16*)(ws + (size_t)16875520);                // 128 MB (lower-tri used)
    unsigned* pmG    = (unsigned*)(ws + (size_t)151093248);               // 32 KB
    unsigned* nmG    = (unsigned*)(ws + (size_t)151126016);               // 32 KB
    unsigned* smG    = (unsigned*)(ws + (size_t)151158784);               // 32 KB

    static bool attr_set = false;
    if (!attr_set) {
        hipFuncSetAttribute((const void*)gemm_kernel,
                            hipFuncAttributeMaxDynamicSharedMemorySize, 131072);
        attr_set = true;
    }

    prep_kernel<<<N / 4, 256, 0, stream>>>(E, target, Ebf, sq, cls, pmG, nmG, smG);
    gemm_kernel<<<592, 512, 131072, stream>>>(Ebf, sq, cls, D2h, pmG, nmG);
    mine2_kernel<<<592, 512, 0, stream>>>(D2h, pmG, smG);
    finalize_kernel<<<N / 256, 256, 0, stream>>>(pmG, nmG, smG, loss_arr);
    reduce_kernel<<<1, 256, 0, stream>>>(loss_arr, out);
}

// Round 11
// 185.410 us; speedup vs baseline: 1.1031x; 1.1031x over previous
//
#include <hip/hip_runtime.h>
#include <hip/hip_bf16.h>

#define N 8192
#define D 1024
#define MARGIN 1.0f
#define EPS 1e-6f

typedef __attribute__((ext_vector_type(8))) short bf16x8;
typedef __attribute__((ext_vector_type(4))) float f32x4;
typedef __attribute__((ext_vector_type(8))) _Float16 f16x8;
typedef __attribute__((ext_vector_type(4))) _Float16 f16x4;
typedef __attribute__((ext_vector_type(8))) unsigned short u16x8;

__device__ inline unsigned short f2bf(float x) {
    unsigned u = __float_as_uint(x);
    unsigned r = (u + 0x7FFFu + ((u >> 16) & 1u)) >> 16;  // RNE
    return (unsigned short)r;
}

__device__ inline float h2f(unsigned hb) {
    return (float)__builtin_bit_cast(_Float16, (unsigned short)hb);
}

// Kernel 0: fp32 -> bf16 copy + per-row sum of squares + cls. One row per
// WAVE (4 rows/block, no LDS, no barriers): 64 lanes x float4 = 1024 floats.
__global__ __launch_bounds__(256) void prep_kernel(const float* __restrict__ E,
                                                   const int* __restrict__ target,
                                                   unsigned short* __restrict__ Ebf,
                                                   float* __restrict__ sq,
                                                   unsigned char* __restrict__ cls) {
    const int tid = threadIdx.x;
    const int lane = tid & 63, wave = tid >> 6;
    const int r = blockIdx.x * 4 + wave;
    const float4 v = ((const float4*)(E + (size_t)r * D))[lane];
    ushort4 o;
    o.x = f2bf(v.x); o.y = f2bf(v.y); o.z = f2bf(v.z); o.w = f2bf(v.w);
    ((ushort4*)(Ebf + (size_t)r * D))[lane] = o;
    float s = v.x * v.x + v.y * v.y + v.z * v.z + v.w * v.w;
    for (int off = 32; off > 0; off >>= 1) s += __shfl_down(s, off);
    if (lane == 0) {
        sq[r] = s;
        cls[r] = (unsigned char)target[r];
    }
}

// ---------------------------------------------------------------------------
// Kernel 1 (merged): ids 0..495 = strict-lower 256^2 tiles, 8-phase schedule,
// R8 row-major decode + XCD swizzle (fastest measured: 92.6us; R9's band
// order cut FETCH 40MB but slowed the loop; R10's folded reductions cost 13us
// of VALU/atomics). ids 496..591 = diag 128^2 lights, dispatched last.
// Epilogue: both tiles through LDS, streamed as full 512B rows (R6-best).
// ---------------------------------------------------------------------------

#define SLOT_0A0 0
#define SLOT_0A1 16384
#define SLOT_0B0 32768
#define SLOT_0B1 49152
#define SLOT_1A0 65536
#define SLOT_1A1 81920
#define SLOT_1B0 98304
#define SLOT_1B1 114688

#define VMW(n) __asm__ __volatile__("s_waitcnt vmcnt(" #n ")" ::: "memory")
#define NOSTAGE ((void)0)
#define NOWAIT ((void)0)

// Stage one 16 KB half-tile (256 rows x 32 bf16) = 2 global_load_lds x 16B/lane.
// LDS dest is linear; the chunk swizzle is applied on the GLOBAL source address.
#define STAGE(slotOff, baseRow, kcol) do {                                              \
    const unsigned short* _s0 = E + (size_t)((baseRow) + (tid >> 2)) * D + (kcol) + stc * 8; \
    __builtin_amdgcn_global_load_lds(                                                    \
        (const __attribute__((address_space(1))) unsigned int*)_s0,                      \
        (__attribute__((address_space(3))) unsigned int*)(smem + (slotOff) + wave * 1024), 16, 0, 0); \
    const unsigned short* _s1 = _s0 + (size_t)128 * D;                                   \
    __builtin_amdgcn_global_load_lds(                                                    \
        (const __attribute__((address_space(1))) unsigned int*)_s1,                      \
        (__attribute__((address_space(3))) unsigned int*)(smem + (slotOff) + 8192 + wave * 1024), 16, 0, 0); \
} while (0)

// One phase: ds-read subtile | optional stage | setprio(1) 16 MFMA setprio(0)
// | optional counted vmcnt | single barrier.
#define PHASE(b, ks, mq, LOADB, STG, WAIT) do {                                          \
    const char* _As = smem + (b) * 65536 + (ks) * 16384;                                 \
    const char* _Bs = smem + (b) * 65536 + 32768 + (ks) * 16384;                         \
    if (LOADB) {                                                                         \
        _Pragma("unroll") for (int nj = 0; nj < 4; ++nj)                                 \
            bfr[nj] = *(const bf16x8*)(_Bs + (wn * 64 + nj * 16 + mr) * 64 + swz);       \
    }                                                                                    \
    bf16x8 af[4];                                                                        \
    _Pragma("unroll") for (int mi = 0; mi < 4; ++mi)                                     \
        af[mi] = *(const bf16x8*)(_As + (wm * 128 + (mq) * 64 + mi * 16 + mr) * 64 + swz); \
    STG;                                                                                 \
    __builtin_amdgcn_s_setprio(1);                                                       \
    _Pragma("unroll") for (int mi = 0; mi < 4; ++mi)                                     \
        _Pragma("unroll") for (int nj = 0; nj < 4; ++nj)                                 \
            acc[(mq) * 4 + mi][nj] = __builtin_amdgcn_mfma_f32_16x16x32_bf16(            \
                af[mi], bfr[nj], acc[(mq) * 4 + mi][nj], 0, 0, 0);                       \
    __builtin_amdgcn_s_setprio(0);                                                       \
    WAIT;                                                                                \
    __asm__ __volatile__("s_barrier" ::: "memory");                                      \
} while (0)

// Light path: one 128^2 diagonal sub-tile, 512 threads / 8 waves (each 64x32),
// 4-slot LDS ring, counted vmcnt(4), last 2 iterations peeled.
__device__ __forceinline__ void diag_path(char* smem,
                                          const unsigned short* __restrict__ E,
                                          const float* __restrict__ sq,
                                          _Float16* __restrict__ D2h,
                                          const int c, const int tid) {
    const int lane = tid & 63;
    const int wave = tid >> 6;           // 0..7
    const int wmL = wave >> 2;           // 0..1 : 64-row half
    const int wnL = wave & 3;            // 0..3 : 32-col quarter
    const int mr = lane & 15;
    const int q = lane >> 4;
    const int kq = q * 8;

    const int t = c / 3, s = c - 3 * t;
    const int smi = (s + 1) >> 1;        // 0,1,1
    const int sni = s >> 1;              // 0,0,1
    const int rm = t * 256 + smi * 128;
    const int cn = t * 256 + sni * 128;
    const bool offdiag = (s == 1);

    f32x4 acc[4][2] = {};

#define DSTAGE(sl, kk) do {                                                              \
    __builtin_amdgcn_global_load_lds(                                                    \
        (const __attribute__((address_space(1))) unsigned int*)(E + (size_t)(rm + (tid >> 2)) * D + (kk) * 32 + (tid & 3) * 8), \
        (__attribute__((address_space(3))) unsigned int*)(smem + (sl) * 32768 + wave * 1024), 16, 0, 0); \
    __builtin_amdgcn_global_load_lds(                                                    \
        (const __attribute__((address_space(1))) unsigned int*)(E + (size_t)(cn + (tid >> 2)) * D + (kk) * 32 + (tid & 3) * 8), \
        (__attribute__((address_space(3))) unsigned int*)(smem + (sl) * 32768 + 16384 + wave * 1024), 16, 0, 0); \
} while (0)

#define DCOMPUTE(k) do {                                                                 \
    const unsigned short* As = (const unsigned short*)(smem + (size_t)((k) & 3) * 32768);\
    const unsigned short* Bs = As + 8192;                                                \
    bf16x8 af[4], bfv[2];                                                                \
    _Pragma("unroll") for (int mi = 0; mi < 4; ++mi)                                     \
        af[mi] = *(const bf16x8*)(As + (wmL * 64 + mi * 16 + mr) * 32 + kq);             \
    _Pragma("unroll") for (int ni = 0; ni < 2; ++ni)                                     \
        bfv[ni] = *(const bf16x8*)(Bs + (wnL * 32 + ni * 16 + mr) * 32 + kq);            \
    _Pragma("unroll") for (int mi = 0; mi < 4; ++mi)                                     \
        _Pragma("unroll") for (int ni = 0; ni < 2; ++ni)                                 \
            acc[mi][ni] = __builtin_amdgcn_mfma_f32_16x16x32_bf16(af[mi], bfv[ni], acc[mi][ni], 0, 0, 0); \
} while (0)

    DSTAGE(0, 0);
    DSTAGE(1, 1);
    for (int k = 0; k < 30; ++k) {
        DSTAGE((k + 2) & 3, k + 2);
        __asm__ __volatile__("s_waitcnt vmcnt(4)" ::: "memory");
        __asm__ __volatile__("s_barrier" ::: "memory");
        DCOMPUTE(k);
    }
    __asm__ __volatile__("s_waitcnt vmcnt(2)" ::: "memory");
    __asm__ __volatile__("s_barrier" ::: "memory");
    DCOMPUTE(30);
    __asm__ __volatile__("s_waitcnt vmcnt(0)" ::: "memory");
    __asm__ __volatile__("s_barrier" ::: "memory");
    DCOMPUTE(31);
#undef DSTAGE
#undef DCOMPUTE
    __syncthreads();   // compute reads complete before smem reuse as Ts

    _Float16* Ts = (_Float16*)smem;      // 128 x (stride 136) fp16
    float sqjL[2];
#pragma unroll
    for (int ni = 0; ni < 2; ++ni) sqjL[ni] = sq[cn + wnL * 32 + ni * 16 + mr];
#pragma unroll
    for (int mi = 0; mi < 4; ++mi) {
        const int lrow = wmL * 64 + mi * 16 + q * 4;
        const int i0 = rm + lrow;
        const f32x4 sqi = *(const f32x4*)(sq + i0);
#pragma unroll
        for (int ni = 0; ni < 2; ++ni) {
            const int lcol = wnL * 32 + ni * 16 + mr;
            const int j = cn + lcol;
            f16x4 tv;
#pragma unroll
            for (int r = 0; r < 4; ++r) {
                const float d2 = fmaxf(sqi[r] + sqjL[ni] - 2.0f * acc[mi][ni][r], 0.0f);
                const _Float16 h = (_Float16)d2;
                D2h[(size_t)(i0 + r) * N + j] = h;
                tv[r] = h;
            }
            if (offdiag)
                *(f16x4*)(Ts + (size_t)lcol * 136 + lrow) = tv;
        }
    }
    if (offdiag) {
        __syncthreads();
#pragma unroll
        for (int it = 0; it < 4; ++it) {
            const int rt = it * 32 + (tid >> 4);
            const int seg = tid & 15;
            f16x8 v = *(const f16x8*)(Ts + (size_t)rt * 136 + seg * 8);
            *(f16x8*)(D2h + (size_t)(cn + rt) * N + rm + seg * 8) = v;
        }
    }
}

__global__ __launch_bounds__(512, 2) void gemm_kernel(const unsigned short* __restrict__ E,
                                                      const float* __restrict__ sq,
                                                      _Float16* __restrict__ D2h) {
    extern __shared__ char smem[];

    const int tid = threadIdx.x;            // 0..511

    if (blockIdx.x >= 496) {                // light diagonal blocks, dispatched last
        diag_path(smem, E, sq, D2h, blockIdx.x - 496, tid);
        return;
    }

    const int lane = tid & 63;
    const int wave = tid >> 6;              // 0..7
    const int wm = wave >> 2;               // M-half (128 rows)
    const int wn = wave & 3;                // N-quarter (64 cols)
    const int mr = lane & 15;
    const int q = lane >> 4;
    const int swz = ((q ^ ((mr >> 1) & 3)) << 4);   // ds_read chunk swizzle
    const int stc = (tid & 3) ^ ((tid >> 3) & 3);   // stage source chunk (inverse swz)

    // R8 row-major decode + XCD swizzle (496 % 8 == 0) -- fastest measured.
    const int h = blockIdx.x;
    const int l = (h & 7) * 62 + (h >> 3);
    int by = (int)((1.0f + sqrtf(8.0f * (float)l + 1.0f)) * 0.5f);
    while (by * (by - 1) / 2 > l) --by;
    while ((by + 1) * by / 2 <= l) ++by;
    const int bx = l - by * (by - 1) / 2;
    const int rm = by * 256;
    const int cn = bx * 256;

    f32x4 acc[8][4] = {};
    bf16x8 bfr[4];

    // Prologue: stage 5 half-tiles (T0 complete + T1.A0), wait oldest 2 done.
    STAGE(SLOT_0A0, rm, 0);
    STAGE(SLOT_0B0, cn, 0);
    STAGE(SLOT_0A1, rm, 32);
    STAGE(SLOT_0B1, cn, 32);
    STAGE(SLOT_1A0, rm, 64);
    VMW(6);
    __asm__ __volatile__("s_barrier" ::: "memory");

    for (int i = 0; i < 7; ++i) {
        const int kt = 2 * i;
        PHASE(0, 0, 0, 1, STAGE(SLOT_1B0, cn, (kt + 1) * 64 + 0),  NOWAIT);
        PHASE(0, 0, 1, 0, STAGE(SLOT_1A1, rm, (kt + 1) * 64 + 32), VMW(6));
        PHASE(0, 1, 0, 1, STAGE(SLOT_1B1, cn, (kt + 1) * 64 + 32), NOWAIT);
        PHASE(0, 1, 1, 0, STAGE(SLOT_0A0, rm, (kt + 2) * 64 + 0),  VMW(6));
        PHASE(1, 0, 0, 1, STAGE(SLOT_0B0, cn, (kt + 2) * 64 + 0),  NOWAIT);
        PHASE(1, 0, 1, 0, STAGE(SLOT_0A1, rm, (kt + 2) * 64 + 32), VMW(6));
        PHASE(1, 1, 0, 1, STAGE(SLOT_0B1, cn, (kt + 2) * 64 + 32), NOWAIT);
        PHASE(1, 1, 1, 0, STAGE(SLOT_1A0, rm, (kt + 3) * 64 + 0),  VMW(6));
    }
    // Peeled final iteration (kt=14): stage only tile 15's B0/A1/B1;
    // tail waits derived from slot liveness (no redundant restages).
    PHASE(0, 0, 0, 1, STAGE(SLOT_1B0, cn, 15 * 64 + 0),  NOWAIT);
    PHASE(0, 0, 1, 0, STAGE(SLOT_1A1, rm, 15 * 64 + 32), VMW(6));
    PHASE(0, 1, 0, 1, STAGE(SLOT_1B1, cn, 15 * 64 + 32), NOWAIT);
    PHASE(0, 1, 1, 0, NOSTAGE, VMW(4));
    PHASE(1, 0, 0, 1, NOSTAGE, NOWAIT);
    PHASE(1, 0, 1, 0, NOSTAGE, VMW(0));
    PHASE(1, 1, 0, 1, NOSTAGE, NOWAIT);
    PHASE(1, 1, 1, 0, NOSTAGE, NOWAIT);

    // All staging DMA drained (vmcnt hit 0 in the peel); sync before smem reuse.
    __asm__ __volatile__("s_waitcnt lgkmcnt(0)" ::: "memory");
    __asm__ __volatile__("s_barrier" ::: "memory");

    // Epilogue: D2 = max(sq_i + sq_j - 2*acc, 0) -> fp16. Both tiles go
    // through LDS (256x256 fp16 = 128 KB, 16B-chunk XOR swizzle
    // physchunk = logchunk ^ (row&31)) and stream out as half-wave-per-row
    // f16x8 stores: one instruction = two full 512B rows, zero partial lines.
    const int crow = q * 4;
    float sqj[4];
#pragma unroll
    for (int nj = 0; nj < 4; ++nj) sqj[nj] = sq[cn + wn * 64 + nj * 16 + mr];
    float sqiv[8][4];
#pragma unroll
    for (int mg = 0; mg < 8; ++mg) {
        const f32x4 s4 = *(const f32x4*)(sq + rm + wm * 128 + mg * 16 + crow);
#pragma unroll
        for (int r = 0; r < 4; ++r) sqiv[mg][r] = s4[r];
    }

    // ---- pass 1: direct orientation (row = i), scalar b16 LDS writes ----
#pragma unroll
    for (int mg = 0; mg < 8; ++mg) {
        const int ilocb = wm * 128 + mg * 16 + crow;
#pragma unroll
        for (int nj = 0; nj < 4; ++nj) {
            const int jloc = wn * 64 + nj * 16 + mr;
            const unsigned jc = (unsigned)jloc >> 3;          // logical 16B chunk
            const unsigned jo = ((unsigned)jloc & 7) << 1;    // byte in chunk
#pragma unroll
            for (int r = 0; r < 4; ++r) {
                const float d2 = fmaxf(sqiv[mg][r] + sqj[nj] - 2.0f * acc[mg][nj][r], 0.0f);
                const int row = ilocb + r;
                *(_Float16*)(smem + (size_t)row * 512 + ((jc ^ (row & 31)) << 4) + jo) = (_Float16)d2;
            }
        }
    }
    __asm__ __volatile__("s_waitcnt lgkmcnt(0)" ::: "memory");
    __asm__ __volatile__("s_barrier" ::: "memory");
    {
        const int seg = tid & 31;          // 16B chunk within the row
#pragma unroll
        for (int it = 0; it < 16; ++it) {
            const int rt = it * 16 + (tid >> 5);   // direct-tile row
            f16x8 v = *(const f16x8*)(smem + (size_t)rt * 512 + (((unsigned)seg ^ (rt & 31)) << 4));
            *(f16x8*)(D2h + (size_t)(rm + rt) * N + cn + seg * 8) = v;
        }
    }
    __asm__ __volatile__("s_waitcnt lgkmcnt(0)" ::: "memory");
    __asm__ __volatile__("s_barrier" ::: "memory");

    // ---- pass 2: mirror orientation (row = j), packed f16x4 LDS writes ----
#pragma unroll
    for (int mg = 0; mg < 8; ++mg) {
        const int iloc = wm * 128 + mg * 16 + crow;
        const unsigned cch = (unsigned)iloc >> 3;
        const unsigned cof = ((unsigned)iloc & 7) << 1;
#pragma unroll
        for (int nj = 0; nj < 4; ++nj) {
            const int jloc = wn * 64 + nj * 16 + mr;
            f16x4 tv;
#pragma unroll
            for (int r = 0; r < 4; ++r)
                tv[r] = (_Float16)fmaxf(sqiv[mg][r] + sqj[nj] - 2.0f * acc[mg][nj][r], 0.0f);
            *(f16x4*)(smem + (size_t)jloc * 512 + ((cch ^ (jloc & 31)) << 4) + cof) = tv;
        }
    }
    __asm__ __volatile__("s_waitcnt lgkmcnt(0)" ::: "memory");
    __asm__ __volatile__("s_barrier" ::: "memory");
    {
        const int seg = tid & 31;
#pragma unroll
        for (int it = 0; it < 16; ++it) {
            const int rt = it * 16 + (tid >> 5);   // mirror-tile row
            f16x8 v = *(const f16x8*)(smem + (size_t)rt * 512 + (((unsigned)seg ^ (rt & 31)) << 4));
            *(f16x8*)(D2h + (size_t)(cn + rt) * N + rm + seg * 8) = v;
        }
    }
}

// Kernel 2: TWO rows per block; both stashes + cls loaded upfront (row-B HBM
// latency hides under row-A reduce). Non-negative fp16 orders as u16 bits ->
// all reductions are u32 max/min on raw half-bits. Shared shuffle chains.
__global__ __launch_bounds__(256) void mine_kernel(const _Float16* __restrict__ D2h,
                                                   const unsigned char* __restrict__ cls,
                                                   float* __restrict__ loss_arr) {
    const int i0 = blockIdx.x * 2;
    const int tid = threadIdx.x;
    const int lane = tid & 63, wave = tid >> 6;
    const unsigned tcbA = cls[i0];
    const unsigned tcbB = cls[i0 + 1];
    const unsigned short* rowA = (const unsigned short*)(D2h + (size_t)i0 * N);
    const unsigned short* rowB = rowA + N;

    u16x8 va[4], vb[4];
    unsigned long long c8[4];
#pragma unroll
    for (int it = 0; it < 4; ++it) {
        va[it] = *(const u16x8*)(rowA + it * 2048 + tid * 8);
        vb[it] = *(const u16x8*)(rowB + it * 2048 + tid * 8);
        c8[it] = *(const unsigned long long*)(cls + it * 2048 + tid * 8);
    }

    // Pass 1 (both rows): pm = max same-class bits; nm = min diff-class bits.
    unsigned pmA = 0u, nmA = 0xFFFFu, pmB = 0u, nmB = 0xFFFFu;
#pragma unroll
    for (int it = 0; it < 4; ++it) {
#pragma unroll
        for (int e = 0; e < 8; ++e) {
            const unsigned cv = (unsigned)(c8[it] >> (8 * e)) & 0xFFu;
            const unsigned ha = va[it][e];
            const unsigned hb = vb[it][e];
            const bool sA = (cv == tcbA);
            const bool sB = (cv == tcbB);
            pmA = max(pmA, sA ? ha : 0u);
            nmA = min(nmA, sA ? 0xFFFFu : ha);
            pmB = max(pmB, sB ? hb : 0u);
            nmB = min(nmB, sB ? 0xFFFFu : hb);
        }
    }
    for (int off = 1; off < 64; off <<= 1) {
        pmA = max(pmA, (unsigned)__shfl_xor((int)pmA, off));
        nmA = min(nmA, (unsigned)__shfl_xor((int)nmA, off));
        pmB = max(pmB, (unsigned)__shfl_xor((int)pmB, off));
        nmB = min(nmB, (unsigned)__shfl_xor((int)nmB, off));
    }
    __shared__ unsigned redp[2][4], redn[2][4], reds[2][4];
    if (lane == 0) {
        redp[0][wave] = pmA; redn[0][wave] = nmA;
        redp[1][wave] = pmB; redn[1][wave] = nmB;
    }
    __syncthreads();
    pmA = max(max(redp[0][0], redp[0][1]), max(redp[0][2], redp[0][3]));
    nmA = min(min(redn[0][0], redn[0][1]), min(redn[0][2], redn[0][3]));
    pmB = max(max(redp[1][0], redp[1][1]), max(redp[1][2], redp[1][3]));
    nmB = min(min(redn[1][0], redn[1][1]), min(redn[1][2], redn[1][3]));

    // Pass 2 (register stash): sm = min bits strictly above lob.
    unsigned smA = 0xFFFFu, smB = 0xFFFFu;
#pragma unroll
    for (int it = 0; it < 4; ++it) {
#pragma unroll
        for (int e = 0; e < 8; ++e) {
            const unsigned ha = va[it][e];
            const unsigned hb = vb[it][e];
            smA = min(smA, ha > pmA ? ha : 0xFFFFu);
            smB = min(smB, hb > pmB ? hb : 0xFFFFu);
        }
    }
    for (int off = 1; off < 64; off <<= 1) {
        smA = min(smA, (unsigned)__shfl_xor((int)smA, off));
        smB = min(smB, (unsigned)__shfl_xor((int)smB, off));
    }
    if (lane == 0) { reds[0][wave] = smA; reds[1][wave] = smB; }
    __syncthreads();
    if (tid == 0) {
#pragma unroll
        for (int rr = 0; rr < 2; ++rr) {
            const unsigned lob = rr ? pmB : pmA;
            const unsigned nm = rr ? nmB : nmA;
            const unsigned sm = min(min(reds[rr][0], reds[rr][1]),
                                    min(reds[rr][2], reds[rr][3]));
            const float lo = h2f(lob);
            const float dp = sqrtf(lo);
            const float hw = dp + MARGIN;
            const float hi = hw * hw;
            const float smv = h2f(sm);               // 0xFFFF -> NaN -> fallback
            const float dn2 = (smv < hi) ? smv : h2f(nm);
            loss_arr[i0 + rr] = fmaxf(dp - sqrtf(dn2) + MARGIN, 0.0f);
        }
    }
}

// Kernel 3: mean over 8192 per-anchor losses.
__global__ __launch_bounds__(256) void reduce_kernel(const float* __restrict__ loss_arr,
                                                     float* __restrict__ out) {
    const int tid = threadIdx.x;
    float s = 0.0f;
    for (int k = tid; k < N; k += 256) s += loss_arr[k];
    for (int off = 32; off > 0; off >>= 1) s += __shfl_down(s, off);
    __shared__ float red[4];
    const int lane = tid & 63, wave = tid >> 6;
    if (lane == 0) red[wave] = s;
    __syncthreads();
    if (tid == 0) out[0] = (red[0] + red[1] + red[2] + red[3]) * (1.0f / N);
}

extern "C" void kernel_launch(void* const* d_in, const int* in_sizes, int n_in,
                              void* d_out, int out_size, void* d_ws, size_t ws_size,
                              hipStream_t stream) {
    const float* E = (const float*)d_in[0];
    const int* target = (const int*)d_in[1];
    float* out = (float*)d_out;
    char* ws = (char*)d_ws;

    // Workspace layout (~144.1 MB):
    unsigned short* Ebf = (unsigned short*)ws;                            // 16 MB
    float* sq        = (float*)(ws + (size_t)16777216);                   // 32 KB
    float* loss_arr  = (float*)(ws + (size_t)16809984);                   // 32 KB
    unsigned char* cls = (unsigned char*)(ws + (size_t)16842752);         // 8 KB (padded 32 KB)
    _Float16* D2h    = (_Float16*)(ws + (size_t)16875520);                // 128 MB

    static bool attr_set = false;
    if (!attr_set) {
        hipFuncSetAttribute((const void*)gemm_kernel,
                            hipFuncAttributeMaxDynamicSharedMemorySize, 131072);
        attr_set = true;
    }

    prep_kernel<<<N / 4, 256, 0, stream>>>(E, target, Ebf, sq, cls);
    gemm_kernel<<<592, 512, 131072, stream>>>(Ebf, sq, D2h);  // 496 lower-tri + 96 diag-light
    mine_kernel<<<N / 2, 256, 0, stream>>>(D2h, cls, loss_arr);
    reduce_kernel<<<1, 256, 0, stream>>>(loss_arr, out);
}